// Round 1
// baseline (725.280 us; speedup 1.0000x reference)
//
#include <hip/hip_runtime.h>
#include <math.h>

// Problem constants: B=8, L=4096, H=8, E=64, MODES=64, C=H*E=512.
// out = irfft( scatter( einsum-chain( rfft(q)[..,:64], rfft(k)[..,:64], w1+i*w2 ) ) / 2^18, n=4096 )
// Only the lowest 64 bins matter -> truncated DFT (radix-4 folded) + tiny complex GEMMs + truncated iDFT.
// v, index_q, index_kv are unused by the reference.

#define Lt 4096
#define Ct 512
#define Mt 64

// ws layout (float offsets)
#define TWA_OFF   0u                     // [1024 t][128] : cos, -sin interleaved per mode  (512 KB)
#define CTAB_OFF  131072u                // [4096] cos(2*pi*i/4096)
#define STAB_OFF  135168u                // [4096] sin(2*pi*i/4096)
#define QFP_OFF   139264u                // [8 chunk][2 src][8 b][64 m][512 c][2]  (33.5 MB)
#define COEF_OFF  (139264u + 8388608u)   // [64 bh][64 o][128]  (2 MB)
// total ws: 9,052,160 floats = 36.2 MB

__global__ __launch_bounds__(256) void init_tw(float* __restrict__ twa,
                                               float* __restrict__ ctab,
                                               float* __restrict__ stab) {
  int id = blockIdx.x * 256 + threadIdx.x;   // 65536 threads
  int t = id >> 6, m = id & 63;
  int idx = (m * t) & 4095;
  float a = (float)idx * (1.0f / 2048.0f);   // angle = pi*a = 2*pi*idx/4096
  float s, c;
  sincospif(a, &s, &c);
  twa[t * 128 + 2 * m]     = c;
  twa[t * 128 + 2 * m + 1] = -s;             // store -sin: forward DFT e^{-i theta}
  if (id < 4096) {
    float a2 = (float)id * (1.0f / 2048.0f);
    float s2, c2;
    sincospif(a2, &s2, &c2);
    ctab[id] = c2;
    stab[id] = s2;
  }
}

// Stage A: truncated DFT of q and k, radix-4 folded over t.
// grid 256 = b(8) | src(2) | cblk(2) | chunk(8); block 256; lane <-> channel.
__global__ __launch_bounds__(256, 1) void dft_kernel(const float* __restrict__ q,
                                                     const float* __restrict__ k,
                                                     const float* __restrict__ twa,
                                                     float* __restrict__ qfp) {
  const int id   = blockIdx.x;
  const int b    = id & 7;
  const int src  = (id >> 3) & 1;
  const int cblk = (id >> 4) & 1;
  const int ch   = id >> 5;                  // 0..7 k-chunk
  const int c    = cblk * 256 + threadIdx.x;
  const float* __restrict__ x = (src ? k : q) + (size_t)b * (Lt * Ct) + c;

  float acc[128];
#pragma unroll
  for (int j = 0; j < 128; ++j) acc[j] = 0.f;

  const int t0 = ch * 128;
  // software-pipelined prefetch of the 4 radix planes
  float n0 = x[(size_t)(t0)        * Ct];
  float n1 = x[(size_t)(t0 + 1024) * Ct];
  float n2 = x[(size_t)(t0 + 2048) * Ct];
  float n3 = x[(size_t)(t0 + 3072) * Ct];

  for (int t = t0; t < t0 + 128; ++t) {
    const float x0 = n0, x1 = n1, x2 = n2, x3 = n3;
    const int tn = (t + 1 < t0 + 128) ? (t + 1) : t0;   // clamped (in-bounds) prefetch
    n0 = x[(size_t)(tn)        * Ct];
    n1 = x[(size_t)(tn + 1024) * Ct];
    n2 = x[(size_t)(tn + 2048) * Ct];
    n3 = x[(size_t)(tn + 3072) * Ct];

    const float s02 = x0 + x2, s13 = x1 + x3;
    const float A0v = s02 + s13;         // m % 4 == 0
    const float A2v = s02 - s13;         // m % 4 == 2
    const float D0v = x0 - x2;           // odd modes: (D0 -+ i*D1)
    const float D1v = x1 - x3;

    const float* __restrict__ tw = twa + t * 128;   // wave-uniform -> s_load
#pragma unroll
    for (int m4 = 0; m4 < 16; ++m4) {
      {
        const float cc = tw[8 * m4 + 0], ns = tw[8 * m4 + 1];
        acc[8 * m4 + 0] = fmaf(A0v, cc, acc[8 * m4 + 0]);
        acc[8 * m4 + 1] = fmaf(A0v, ns, acc[8 * m4 + 1]);
      }
      { // m%4==1: (D0 - i D1)(cc + i ns)
        const float cc = tw[8 * m4 + 2], ns = tw[8 * m4 + 3];
        acc[8 * m4 + 2] = fmaf(D0v, cc, fmaf(D1v, ns, acc[8 * m4 + 2]));
        acc[8 * m4 + 3] = fmaf(D0v, ns, fmaf(-D1v, cc, acc[8 * m4 + 3]));
      }
      {
        const float cc = tw[8 * m4 + 4], ns = tw[8 * m4 + 5];
        acc[8 * m4 + 4] = fmaf(A2v, cc, acc[8 * m4 + 4]);
        acc[8 * m4 + 5] = fmaf(A2v, ns, acc[8 * m4 + 5]);
      }
      { // m%4==3: (D0 + i D1)(cc + i ns)
        const float cc = tw[8 * m4 + 6], ns = tw[8 * m4 + 7];
        acc[8 * m4 + 6] = fmaf(D0v, cc, fmaf(-D1v, ns, acc[8 * m4 + 6]));
        acc[8 * m4 + 7] = fmaf(D0v, ns, fmaf(D1v, cc, acc[8 * m4 + 7]));
      }
    }
  }

  const int chs = ch * 2 + src;
  float* __restrict__ outp = qfp + (size_t)(chs * 8 + b) * 65536 + (size_t)c * 2;
#pragma unroll
  for (int m = 0; m < Mt; ++m) {
    *(float2*)(outp + (size_t)m * 1024) = make_float2(acc[2 * m], acc[2 * m + 1]);
  }
}

// Stage B: per (b,h,x-quarter): S = Q^T K (complex, no conj) -> tanh -> P = S*K -> project by w.
// grid 256 = bh(64) | xq(4); block 256.
__global__ __launch_bounds__(256) void attn_kernel(const float* __restrict__ qfp,
                                                   const float* __restrict__ w1,
                                                   const float* __restrict__ w2,
                                                   float* __restrict__ coef) {
  __shared__ float Qre[16 * 65], Qim[16 * 65];
  __shared__ float Kre[64 * 65], Kim[64 * 65];
  __shared__ float Sre[16 * 65], Sim[16 * 65];
  __shared__ float Pre[16 * 65], Pim[16 * 65];

  const int bh   = blockIdx.x >> 2;
  const int xq   = blockIdx.x & 3;
  const int b    = bh >> 3;
  const int h    = bh & 7;
  const int lane = threadIdx.x & 63;   // <-> e in the loaders
  const int g    = threadIdx.x >> 6;   // 0..3

  // Load Q modes [xq*16, xq*16+16) and all 64 K modes, summing the 8 split-K partials.
#pragma unroll
  for (int it = 0; it < 4; ++it) {
    const int xi = g + 4 * it;
    const int m  = xq * 16 + xi;
    float re = 0.f, im = 0.f;
#pragma unroll
    for (int ch = 0; ch < 8; ++ch) {
      const float2 v = *(const float2*)(qfp + (size_t)((ch * 2 + 0) * 8 + b) * 65536 +
                                        (size_t)m * 1024 + (size_t)(h * 64 + lane) * 2);
      re += v.x; im += v.y;
    }
    Qre[xi * 65 + lane] = re;
    Qim[xi * 65 + lane] = im;
  }
#pragma unroll
  for (int it = 0; it < 16; ++it) {
    const int y = g + 4 * it;
    float re = 0.f, im = 0.f;
#pragma unroll
    for (int ch = 0; ch < 8; ++ch) {
      const float2 v = *(const float2*)(qfp + (size_t)((ch * 2 + 1) * 8 + b) * 65536 +
                                        (size_t)y * 1024 + (size_t)(h * 64 + lane) * 2);
      re += v.x; im += v.y;
    }
    Kre[y * 65 + lane] = re;
    Kim[y * 65 + lane] = im;
  }
  __syncthreads();

  // B1: S[xi][y] = sum_e Q[e][xi] * K[e][y], then tanh(re), tanh(im)
  {
    const int y = lane;
    float sre[4] = {0, 0, 0, 0}, sim[4] = {0, 0, 0, 0};
    for (int e = 0; e < 64; ++e) {
      const float kr = Kre[y * 65 + e], ki = Kim[y * 65 + e];
#pragma unroll
      for (int kk = 0; kk < 4; ++kk) {
        const int xi = g * 4 + kk;
        const float qr = Qre[xi * 65 + e], qi = Qim[xi * 65 + e];
        sre[kk] = fmaf(qr, kr, fmaf(-qi, ki, sre[kk]));
        sim[kk] = fmaf(qr, ki, fmaf(qi, kr, sim[kk]));
      }
    }
#pragma unroll
    for (int kk = 0; kk < 4; ++kk) {
      const int xi = g * 4 + kk;
      Sre[xi * 65 + y] = tanhf(sre[kk]);
      Sim[xi * 65 + y] = tanhf(sim[kk]);
    }
  }
  __syncthreads();

  // B2: P[e][xi] = sum_y S[xi][y] * K[e][y]
  {
    const int e = lane;
    float pre[4] = {0, 0, 0, 0}, pim[4] = {0, 0, 0, 0};
    for (int y = 0; y < 64; ++y) {
      const float kr = Kre[y * 65 + e], ki = Kim[y * 65 + e];
#pragma unroll
      for (int kk = 0; kk < 4; ++kk) {
        const int xi = g * 4 + kk;
        const float sr = Sre[xi * 65 + y], si = Sim[xi * 65 + y];
        pre[kk] = fmaf(sr, kr, fmaf(-si, ki, pre[kk]));
        pim[kk] = fmaf(sr, ki, fmaf(si, kr, pim[kk]));
      }
    }
#pragma unroll
    for (int kk = 0; kk < 4; ++kk) {
      const int xi = g * 4 + kk;
      Pre[xi * 65 + e] = pre[kk];
      Pim[xi * 65 + e] = pim[kk];
    }
  }
  __syncthreads();

  // B3: Coef[o][2x]   =  2^-30 * (1 or 2) * Re( sum_e P[e][x] * (w1+i w2)[h][e][o][x] )
  //     Coef[o][2x+1] = -2^-30 * (1 or 2) * Im( ... )
  {
    const int xi = threadIdx.x & 15;
    const int og = threadIdx.x >> 4;   // 0..15
    const int x  = xq * 16 + xi;
    float ore[4] = {0, 0, 0, 0}, oim[4] = {0, 0, 0, 0};
#pragma unroll 4
    for (int e = 0; e < 64; ++e) {
      const float ar = Pre[xi * 65 + e], ai = Pim[xi * 65 + e];
#pragma unroll
      for (int kk = 0; kk < 4; ++kk) {
        const int o = og * 4 + kk;
        const size_t widx = (size_t)((h * 64 + e) * 64 + o) * 64 + x;
        const float wr = w1[widx], wi = w2[widx];
        ore[kk] = fmaf(ar, wr, fmaf(-ai, wi, ore[kk]));
        oim[kk] = fmaf(ar, wi, fmaf(ai, wr, oim[kk]));
      }
    }
    const float gs = (x == 0) ? 0x1p-30f : 0x1p-29f;   // 1/(512*512*4096), x2 for m>=1
#pragma unroll
    for (int kk = 0; kk < 4; ++kk) {
      const int o = og * 4 + kk;
      *(float2*)(coef + (size_t)(bh * 64 + o) * 128 + 2 * x) =
          make_float2(gs * ore[kk], -gs * oim[kk]);
    }
  }
}

// Stage C: out[bh][o][t] = sum_{j<128} Coef[o][j] * tw_t[j]
// grid 1024 = bh(64) | tchunk(16); block 256; thread <-> t.
__global__ __launch_bounds__(256, 2) void idft_kernel(const float* __restrict__ coef,
                                                      const float* __restrict__ ctab,
                                                      const float* __restrict__ stab,
                                                      float* __restrict__ out) {
  const int bh = blockIdx.x >> 4;
  const int tc = blockIdx.x & 15;
  const int t  = tc * 256 + threadIdx.x;

  float tw[128];
#pragma unroll
  for (int m = 0; m < Mt; ++m) {
    const int idx = (m * t) & 4095;
    tw[2 * m]     = ctab[idx];
    tw[2 * m + 1] = stab[idx];
  }

  const float* __restrict__ crow = coef + (size_t)bh * 64 * 128;
  float* __restrict__ orow = out + (size_t)bh * 64 * 4096 + t;

  for (int o = 0; o < 64; ++o) {
    const float* __restrict__ cr = crow + o * 128;   // wave-uniform -> s_load
    float a0 = 0.f, a1 = 0.f, a2 = 0.f, a3 = 0.f;
#pragma unroll
    for (int j = 0; j < 128; j += 4) {
      a0 = fmaf(cr[j + 0], tw[j + 0], a0);
      a1 = fmaf(cr[j + 1], tw[j + 1], a1);
      a2 = fmaf(cr[j + 2], tw[j + 2], a2);
      a3 = fmaf(cr[j + 3], tw[j + 3], a3);
    }
    orow[(size_t)o * 4096] = (a0 + a1) + (a2 + a3);
  }
}

extern "C" void kernel_launch(void* const* d_in, const int* in_sizes, int n_in,
                              void* d_out, int out_size, void* d_ws, size_t ws_size,
                              hipStream_t stream) {
  (void)in_sizes; (void)n_in; (void)out_size; (void)ws_size;
  const float* q  = (const float*)d_in[0];
  const float* k  = (const float*)d_in[1];
  // d_in[2] (v), d_in[5], d_in[6] (indices) are unused by the reference.
  const float* w1 = (const float*)d_in[3];
  const float* w2 = (const float*)d_in[4];
  float* ws   = (float*)d_ws;
  float* outp = (float*)d_out;

  float* twa  = ws + TWA_OFF;
  float* ctab = ws + CTAB_OFF;
  float* stab = ws + STAB_OFF;
  float* qfp  = ws + QFP_OFF;
  float* coef = ws + COEF_OFF;

  init_tw<<<256, 256, 0, stream>>>(twa, ctab, stab);
  dft_kernel<<<256, 256, 0, stream>>>(q, k, twa, qfp);
  attn_kernel<<<256, 256, 0, stream>>>(qfp, w1, w2, coef);
  idft_kernel<<<1024, 256, 0, stream>>>(coef, ctab, stab, outp);
}

// Round 2
// 454.468 us; speedup vs baseline: 1.5959x; 1.5959x over previous
//
#include <hip/hip_runtime.h>
#include <math.h>

// Problem constants: B=8, L=4096, H=8, E=64, MODES=64, C=H*E=512.
// Only the lowest 64 bins matter -> truncated DFT (radix-4 folded) + tiny complex GEMMs + truncated iDFT.
// v, index_q, index_kv are unused by the reference.

#define Lt 4096
#define Ct 512
#define Mt 64

// ws layout (float offsets)
#define TWA_OFF   0u                      // [1024 t][128] : cos, -sin interleaved per mode (512 KB)
#define TWJ_OFF   131072u                 // [128 j][4096 t] : j=2m -> cos(2pi m t/L), j=2m+1 -> sin (2 MB)
#define QFP_OFF   655360u                 // [8 chunk][2 src][8 b][64 m][512 c][2]  (33.5 MB)
#define COEF_OFF  9043968u                // [64 bh][64 o][128]  (2 MB)
// total ws: 9,568,256 floats = 38.3 MB

__global__ __launch_bounds__(256) void init_tw(float* __restrict__ twa) {
  int id = blockIdx.x * 256 + threadIdx.x;   // 65536 threads
  int t = id >> 6, m = id & 63;
  int idx = (m * t) & 4095;
  float a = (float)idx * (1.0f / 2048.0f);   // angle = pi*a = 2*pi*idx/4096
  float s, c;
  sincospif(a, &s, &c);
  twa[t * 128 + 2 * m]     = c;
  twa[t * 128 + 2 * m + 1] = -s;             // forward DFT e^{-i theta}
}

__global__ __launch_bounds__(256) void init_twj(float* __restrict__ twj) {
  int id = blockIdx.x * 256 + threadIdx.x;   // 524288 threads
  int j = id >> 12, t = id & 4095;
  int m = j >> 1;
  int idx = (m * t) & 4095;
  float a = (float)idx * (1.0f / 2048.0f);
  float s, c;
  sincospif(a, &s, &c);
  twj[id] = (j & 1) ? s : c;                 // inverse side: +sin
}

// Stage A: truncated DFT of q and k, radix-4 folded over t.
// grid 256 = b(8) | src(2) | cblk(2) | chunk(8); block 256; lane <-> channel.
__global__ __launch_bounds__(256, 1) void dft_kernel(const float* __restrict__ q,
                                                     const float* __restrict__ k,
                                                     const float* __restrict__ twa,
                                                     float* __restrict__ qfp) {
  const int id   = blockIdx.x;
  const int b    = id & 7;
  const int src  = (id >> 3) & 1;
  const int cblk = (id >> 4) & 1;
  const int ch   = id >> 5;                  // 0..7 k-chunk
  const int c    = cblk * 256 + threadIdx.x;
  const float* __restrict__ x = (src ? k : q) + (size_t)b * (Lt * Ct) + c;

  float acc[128];
#pragma unroll
  for (int j = 0; j < 128; ++j) acc[j] = 0.f;

  const int t0 = ch * 128;
  float n0 = x[(size_t)(t0)        * Ct];
  float n1 = x[(size_t)(t0 + 1024) * Ct];
  float n2 = x[(size_t)(t0 + 2048) * Ct];
  float n3 = x[(size_t)(t0 + 3072) * Ct];

  for (int t = t0; t < t0 + 128; ++t) {
    const float x0 = n0, x1 = n1, x2 = n2, x3 = n3;
    const int tn = (t + 1 < t0 + 128) ? (t + 1) : t0;   // clamped (in-bounds) prefetch
    n0 = x[(size_t)(tn)        * Ct];
    n1 = x[(size_t)(tn + 1024) * Ct];
    n2 = x[(size_t)(tn + 2048) * Ct];
    n3 = x[(size_t)(tn + 3072) * Ct];

    const float s02 = x0 + x2, s13 = x1 + x3;
    const float A0v = s02 + s13;         // m % 4 == 0
    const float A2v = s02 - s13;         // m % 4 == 2
    const float D0v = x0 - x2;           // odd modes: (D0 -+ i*D1)
    const float D1v = x1 - x3;

    const float* __restrict__ tw = twa + t * 128;   // wave-uniform
#pragma unroll
    for (int m4 = 0; m4 < 16; ++m4) {
      {
        const float cc = tw[8 * m4 + 0], ns = tw[8 * m4 + 1];
        acc[8 * m4 + 0] = fmaf(A0v, cc, acc[8 * m4 + 0]);
        acc[8 * m4 + 1] = fmaf(A0v, ns, acc[8 * m4 + 1]);
      }
      { // m%4==1: (D0 - i D1)(cc + i ns)
        const float cc = tw[8 * m4 + 2], ns = tw[8 * m4 + 3];
        acc[8 * m4 + 2] = fmaf(D0v, cc, fmaf(D1v, ns, acc[8 * m4 + 2]));
        acc[8 * m4 + 3] = fmaf(D0v, ns, fmaf(-D1v, cc, acc[8 * m4 + 3]));
      }
      {
        const float cc = tw[8 * m4 + 4], ns = tw[8 * m4 + 5];
        acc[8 * m4 + 4] = fmaf(A2v, cc, acc[8 * m4 + 4]);
        acc[8 * m4 + 5] = fmaf(A2v, ns, acc[8 * m4 + 5]);
      }
      { // m%4==3: (D0 + i D1)(cc + i ns)
        const float cc = tw[8 * m4 + 6], ns = tw[8 * m4 + 7];
        acc[8 * m4 + 6] = fmaf(D0v, cc, fmaf(-D1v, ns, acc[8 * m4 + 6]));
        acc[8 * m4 + 7] = fmaf(D0v, ns, fmaf(D1v, cc, acc[8 * m4 + 7]));
      }
    }
  }

  const int chs = ch * 2 + src;
  float* __restrict__ outp = qfp + (size_t)(chs * 8 + b) * 65536 + (size_t)c * 2;
#pragma unroll
  for (int m = 0; m < Mt; ++m) {
    *(float2*)(outp + (size_t)m * 1024) = make_float2(acc[2 * m], acc[2 * m + 1]);
  }
}

// Stage B: per (b,h,x-quarter): S = Q^T K (complex, no conj) -> tanh -> P = S*K -> project by w.
// grid 256 = bh(64) | xq(4); block 256.
__global__ __launch_bounds__(256) void attn_kernel(const float* __restrict__ qfp,
                                                   const float* __restrict__ w1,
                                                   const float* __restrict__ w2,
                                                   float* __restrict__ coef) {
  __shared__ float Qre[16 * 65], Qim[16 * 65];
  __shared__ float Kre[64 * 65], Kim[64 * 65];
  __shared__ float Sre[16 * 65], Sim[16 * 65];
  __shared__ float Pre[16 * 65], Pim[16 * 65];

  const int bh   = blockIdx.x >> 2;
  const int xq   = blockIdx.x & 3;
  const int b    = bh >> 3;
  const int h    = bh & 7;
  const int lane = threadIdx.x & 63;   // <-> e in the loaders
  const int g    = threadIdx.x >> 6;   // 0..3

#pragma unroll
  for (int it = 0; it < 4; ++it) {
    const int xi = g + 4 * it;
    const int m  = xq * 16 + xi;
    float re = 0.f, im = 0.f;
#pragma unroll
    for (int ch = 0; ch < 8; ++ch) {
      const float2 v = *(const float2*)(qfp + (size_t)((ch * 2 + 0) * 8 + b) * 65536 +
                                        (size_t)m * 1024 + (size_t)(h * 64 + lane) * 2);
      re += v.x; im += v.y;
    }
    Qre[xi * 65 + lane] = re;
    Qim[xi * 65 + lane] = im;
  }
#pragma unroll
  for (int it = 0; it < 16; ++it) {
    const int y = g + 4 * it;
    float re = 0.f, im = 0.f;
#pragma unroll
    for (int ch = 0; ch < 8; ++ch) {
      const float2 v = *(const float2*)(qfp + (size_t)((ch * 2 + 1) * 8 + b) * 65536 +
                                        (size_t)y * 1024 + (size_t)(h * 64 + lane) * 2);
      re += v.x; im += v.y;
    }
    Kre[y * 65 + lane] = re;
    Kim[y * 65 + lane] = im;
  }
  __syncthreads();

  // B1: S[xi][y] = sum_e Q[e][xi] * K[e][y], then tanh per part
  {
    const int y = lane;
    float sre[4] = {0, 0, 0, 0}, sim[4] = {0, 0, 0, 0};
    for (int e = 0; e < 64; ++e) {
      const float kr = Kre[y * 65 + e], ki = Kim[y * 65 + e];
#pragma unroll
      for (int kk = 0; kk < 4; ++kk) {
        const int xi = g * 4 + kk;
        const float qr = Qre[xi * 65 + e], qi = Qim[xi * 65 + e];
        sre[kk] = fmaf(qr, kr, fmaf(-qi, ki, sre[kk]));
        sim[kk] = fmaf(qr, ki, fmaf(qi, kr, sim[kk]));
      }
    }
#pragma unroll
    for (int kk = 0; kk < 4; ++kk) {
      const int xi = g * 4 + kk;
      Sre[xi * 65 + y] = tanhf(sre[kk]);
      Sim[xi * 65 + y] = tanhf(sim[kk]);
    }
  }
  __syncthreads();

  // B2: P[e][xi] = sum_y S[xi][y] * K[e][y]
  {
    const int e = lane;
    float pre[4] = {0, 0, 0, 0}, pim[4] = {0, 0, 0, 0};
    for (int y = 0; y < 64; ++y) {
      const float kr = Kre[y * 65 + e], ki = Kim[y * 65 + e];
#pragma unroll
      for (int kk = 0; kk < 4; ++kk) {
        const int xi = g * 4 + kk;
        const float sr = Sre[xi * 65 + y], si = Sim[xi * 65 + y];
        pre[kk] = fmaf(sr, kr, fmaf(-si, ki, pre[kk]));
        pim[kk] = fmaf(sr, ki, fmaf(si, kr, pim[kk]));
      }
    }
#pragma unroll
    for (int kk = 0; kk < 4; ++kk) {
      const int xi = g * 4 + kk;
      Pre[xi * 65 + e] = pre[kk];
      Pim[xi * 65 + e] = pim[kk];
    }
  }
  __syncthreads();

  // B3: project by w = w1 + i w2, fold scale and irfft's conj-symmetry factor
  {
    const int xi = threadIdx.x & 15;
    const int og = threadIdx.x >> 4;   // 0..15
    const int x  = xq * 16 + xi;
    float ore[4] = {0, 0, 0, 0}, oim[4] = {0, 0, 0, 0};
#pragma unroll 4
    for (int e = 0; e < 64; ++e) {
      const float ar = Pre[xi * 65 + e], ai = Pim[xi * 65 + e];
#pragma unroll
      for (int kk = 0; kk < 4; ++kk) {
        const int o = og * 4 + kk;
        const size_t widx = (size_t)((h * 64 + e) * 64 + o) * 64 + x;
        const float wr = w1[widx], wi = w2[widx];
        ore[kk] = fmaf(ar, wr, fmaf(-ai, wi, ore[kk]));
        oim[kk] = fmaf(ar, wi, fmaf(ai, wr, oim[kk]));
      }
    }
    const float gs = (x == 0) ? 0x1p-30f : 0x1p-29f;   // 1/(512*512*4096), x2 for m>=1
#pragma unroll
    for (int kk = 0; kk < 4; ++kk) {
      const int o = og * 4 + kk;
      *(float2*)(coef + (size_t)(bh * 64 + o) * 128 + 2 * x) =
          make_float2(gs * ore[kk], -gs * oim[kk]);
    }
  }
}

// Stage C: out[bh][o][t] = sum_{j<128} Coef[o][j] * TW[j][t]
// grid 1024 = bh(64) | tchunk(16); block 256; thread <-> t.
// launch_bounds(256,1): tw[128] MUST stay in VGPRs (round-1 spill was the 425us bug).
__global__ __launch_bounds__(256, 1) void idft_kernel(const float* __restrict__ coef,
                                                      const float* __restrict__ twj,
                                                      float* __restrict__ out) {
  const int bh = blockIdx.x >> 4;
  const int tc = blockIdx.x & 15;
  const int t  = tc * 256 + threadIdx.x;

  float tw[128];
#pragma unroll
  for (int j = 0; j < 128; ++j) tw[j] = twj[(size_t)j * 4096 + t];   // coalesced rows

  const float* __restrict__ crow = coef + (size_t)bh * 64 * 128;
  float* __restrict__ orow = out + (size_t)bh * 64 * 4096 + t;

#pragma unroll 1
  for (int o = 0; o < 64; o += 2) {
    const float* __restrict__ cr0 = crow + o * 128;       // uniform address -> broadcast
    const float* __restrict__ cr1 = cr0 + 128;
    float a0 = 0.f, a1 = 0.f, a2 = 0.f, a3 = 0.f;
    float b0 = 0.f, b1 = 0.f, b2 = 0.f, b3 = 0.f;
#pragma unroll
    for (int j = 0; j < 128; j += 4) {
      const float4 c0 = *(const float4*)(cr0 + j);
      const float4 c1 = *(const float4*)(cr1 + j);
      a0 = fmaf(c0.x, tw[j + 0], a0);
      a1 = fmaf(c0.y, tw[j + 1], a1);
      a2 = fmaf(c0.z, tw[j + 2], a2);
      a3 = fmaf(c0.w, tw[j + 3], a3);
      b0 = fmaf(c1.x, tw[j + 0], b0);
      b1 = fmaf(c1.y, tw[j + 1], b1);
      b2 = fmaf(c1.z, tw[j + 2], b2);
      b3 = fmaf(c1.w, tw[j + 3], b3);
    }
    orow[(size_t)o * 4096]       = (a0 + a1) + (a2 + a3);
    orow[(size_t)(o + 1) * 4096] = (b0 + b1) + (b2 + b3);
  }
}

extern "C" void kernel_launch(void* const* d_in, const int* in_sizes, int n_in,
                              void* d_out, int out_size, void* d_ws, size_t ws_size,
                              hipStream_t stream) {
  (void)in_sizes; (void)n_in; (void)out_size; (void)ws_size;
  const float* q  = (const float*)d_in[0];
  const float* k  = (const float*)d_in[1];
  // d_in[2] (v), d_in[5], d_in[6] (indices) are unused by the reference.
  const float* w1 = (const float*)d_in[3];
  const float* w2 = (const float*)d_in[4];
  float* ws   = (float*)d_ws;
  float* outp = (float*)d_out;

  float* twa  = ws + TWA_OFF;
  float* twj  = ws + TWJ_OFF;
  float* qfp  = ws + QFP_OFF;
  float* coef = ws + COEF_OFF;

  init_tw<<<256, 256, 0, stream>>>(twa);
  init_twj<<<2048, 256, 0, stream>>>(twj);
  dft_kernel<<<256, 256, 0, stream>>>(q, k, twa, qfp);
  attn_kernel<<<256, 256, 0, stream>>>(qfp, w1, w2, coef);
  idft_kernel<<<1024, 256, 0, stream>>>(coef, twj, outp);
}

// Round 3
// 366.599 us; speedup vs baseline: 1.9784x; 1.2397x over previous
//
#include <hip/hip_runtime.h>
#include <math.h>

// B=8, L=4096, H=8, E=64, MODES=64, C=512. Truncated DFT + tiny complex GEMMs + truncated iDFT.
// v, index_q, index_kv unused by the reference.

#define Lt 4096
#define Ct 512
#define Mt 64

// ws layout (float offsets)
#define TWA_OFF   0u                      // [1024 t][128]: cos,-sin per mode (512 KB)
#define TWJ_OFF   131072u                 // [128 j][4096 t]: j=2m -> cos, j=2m+1 -> +sin (2 MB)
#define QFP_OFF   655360u                 // [8 chunk][2 src][8 b][64 m][512 c][2]  (33.5 MB)
#define COEF_OFF  9043968u                // coefT: [64 bh][128 j][64 o]  (2 MB)

__global__ __launch_bounds__(256) void init_tw(float* __restrict__ twa) {
  int id = blockIdx.x * 256 + threadIdx.x;   // 65536
  int t = id >> 6, m = id & 63;
  int idx = (m * t) & 4095;
  float a = (float)idx * (1.0f / 2048.0f);
  float s, c;
  sincospif(a, &s, &c);
  twa[t * 128 + 2 * m]     = c;
  twa[t * 128 + 2 * m + 1] = -s;
}

__global__ __launch_bounds__(256) void init_twj(float* __restrict__ twj) {
  int id = blockIdx.x * 256 + threadIdx.x;   // 524288
  int j = id >> 12, t = id & 4095;
  int m = j >> 1;
  int idx = (m * t) & 4095;
  float a = (float)idx * (1.0f / 2048.0f);
  float s, c;
  sincospif(a, &s, &c);
  twj[id] = (j & 1) ? s : c;
}

// Stage A: truncated DFT, radix-4 folded. grid 1024 = mg(2b)|ch(3b)|cblk(1b)|src(1b)|b(3b).
// mg in top bits: the 4 blocks re-reading the same x slab are id, id+256, id+512, id+768 ->
// same (id%8) XCD -> shared L2. acc[32] per thread (16 modes) -> no spill pressure.
__global__ __launch_bounds__(256, 1) void dft_kernel(const float* __restrict__ q,
                                                     const float* __restrict__ k,
                                                     const float* __restrict__ twa,
                                                     float* __restrict__ qfp) {
  const int id   = blockIdx.x;
  const int b    = id & 7;
  const int src  = (id >> 3) & 1;
  const int cblk = (id >> 4) & 1;
  const int ch   = (id >> 5) & 7;            // t-chunk
  const int mg   = (id >> 8) & 3;            // mode quarter: modes [mg*16, mg*16+16)
  const int c    = cblk * 256 + threadIdx.x;
  const float* __restrict__ x = (src ? k : q) + (size_t)b * (Lt * Ct) + c;

  float acc[32];
#pragma unroll
  for (int j = 0; j < 32; ++j) acc[j] = 0.f;

  const int t0 = ch * 128;
  float n0 = x[(size_t)(t0)        * Ct];
  float n1 = x[(size_t)(t0 + 1024) * Ct];
  float n2 = x[(size_t)(t0 + 2048) * Ct];
  float n3 = x[(size_t)(t0 + 3072) * Ct];

  for (int t = t0; t < t0 + 128; ++t) {
    const float x0 = n0, x1 = n1, x2 = n2, x3 = n3;
    const int tn = (t + 1 < t0 + 128) ? (t + 1) : t0;
    n0 = x[(size_t)(tn)        * Ct];
    n1 = x[(size_t)(tn + 1024) * Ct];
    n2 = x[(size_t)(tn + 2048) * Ct];
    n3 = x[(size_t)(tn + 3072) * Ct];

    const float s02 = x0 + x2, s13 = x1 + x3;
    const float A0v = s02 + s13;
    const float A2v = s02 - s13;
    const float D0v = x0 - x2;
    const float D1v = x1 - x3;

    const float* __restrict__ tw = twa + t * 128 + mg * 32;   // wave-uniform
#pragma unroll
    for (int l = 0; l < 4; ++l) {          // 4 mode-quads of this quarter
      {
        const float cc = tw[8 * l + 0], ns = tw[8 * l + 1];
        acc[8 * l + 0] = fmaf(A0v, cc, acc[8 * l + 0]);
        acc[8 * l + 1] = fmaf(A0v, ns, acc[8 * l + 1]);
      }
      {
        const float cc = tw[8 * l + 2], ns = tw[8 * l + 3];
        acc[8 * l + 2] = fmaf(D0v, cc, fmaf(D1v, ns, acc[8 * l + 2]));
        acc[8 * l + 3] = fmaf(D0v, ns, fmaf(-D1v, cc, acc[8 * l + 3]));
      }
      {
        const float cc = tw[8 * l + 4], ns = tw[8 * l + 5];
        acc[8 * l + 4] = fmaf(A2v, cc, acc[8 * l + 4]);
        acc[8 * l + 5] = fmaf(A2v, ns, acc[8 * l + 5]);
      }
      {
        const float cc = tw[8 * l + 6], ns = tw[8 * l + 7];
        acc[8 * l + 6] = fmaf(D0v, cc, fmaf(-D1v, ns, acc[8 * l + 6]));
        acc[8 * l + 7] = fmaf(D0v, ns, fmaf(D1v, cc, acc[8 * l + 7]));
      }
    }
  }

  const int chs = ch * 2 + src;
  float* __restrict__ outp = qfp + (size_t)(chs * 8 + b) * 65536 + (size_t)c * 2;
#pragma unroll
  for (int lm = 0; lm < 16; ++lm) {
    const int m = mg * 16 + lm;
    *(float2*)(outp + (size_t)m * 1024) = make_float2(acc[2 * lm], acc[2 * lm + 1]);
  }
}

// Stage B: one block per (b,h). grid 64; blocks with the same h are id==h (mod 8) -> same XCD,
// so the 2 MB w-slice is fetched once per XCD L2. LDS exactly 64 KB, XOR-swizzled planes:
// plane[r][c] at r*64 + (c ^ (r&31)) -> conflict-free for every access pattern used below.
__global__ __launch_bounds__(256) void attn_kernel(const float* __restrict__ qfp,
                                                   const float* __restrict__ w1,
                                                   const float* __restrict__ w2,
                                                   float* __restrict__ coefT) {
  __shared__ float QS[2][4096];   // Q[x][e]; after B1 overwritten with S[x][y]
  __shared__ float KP[2][4096];   // K[y][e]; after B2 overwritten with P[x][e]

  const int bh   = blockIdx.x;
  const int b    = bh >> 3;
  const int h    = bh & 7;
  const int lane = threadIdx.x & 63;
  const int g    = threadIdx.x >> 6;

  // Load Q (rows m=x) and K (rows y), cols e=lane; sum 8 split-K partials.
#pragma unroll 4
  for (int it = 0; it < 16; ++it) {
    const int r = g + 4 * it;
    float qre = 0.f, qim = 0.f, kre = 0.f, kim = 0.f;
#pragma unroll
    for (int ch = 0; ch < 8; ++ch) {
      const float2 vq = *(const float2*)(qfp + (size_t)((ch * 2 + 0) * 8 + b) * 65536 +
                                         (size_t)r * 1024 + (size_t)(h * 64 + lane) * 2);
      const float2 vk = *(const float2*)(qfp + (size_t)((ch * 2 + 1) * 8 + b) * 65536 +
                                         (size_t)r * 1024 + (size_t)(h * 64 + lane) * 2);
      qre += vq.x; qim += vq.y;
      kre += vk.x; kim += vk.y;
    }
    const int ad = r * 64 + (lane ^ (r & 31));
    QS[0][ad] = qre; QS[1][ad] = qim;
    KP[0][ad] = kre; KP[1][ad] = kim;
  }
  __syncthreads();

  // B1: thread (y=lane, g): S[x][y] = sum_e Q[x][e]*K[y][e], x in [g*16, g*16+16)
  {
    const int y = lane;
    float sr[16], si[16];
#pragma unroll
    for (int i = 0; i < 16; ++i) { sr[i] = 0.f; si[i] = 0.f; }
    for (int e = 0; e < 64; ++e) {
      const int ka = y * 64 + (e ^ (y & 31));
      const float kr = KP[0][ka], ki = KP[1][ka];
#pragma unroll
      for (int xi = 0; xi < 16; ++xi) {
        const int xx = g * 16 + xi;
        const int qa = xx * 64 + (e ^ (xx & 31));   // uniform -> broadcast
        const float qr = QS[0][qa], qi = QS[1][qa];
        sr[xi] = fmaf(qr, kr, fmaf(-qi, ki, sr[xi]));
        si[xi] = fmaf(qr, ki, fmaf(qi, kr, si[xi]));
      }
    }
    __syncthreads();
#pragma unroll
    for (int xi = 0; xi < 16; ++xi) {
      const int xx = g * 16 + xi;
      const int ad = xx * 64 + (y ^ (xx & 31));
      QS[0][ad] = tanhf(sr[xi]);
      QS[1][ad] = tanhf(si[xi]);
    }
  }
  __syncthreads();

  // B2: thread (e=lane, g): P[x][e] = sum_y S[x][y]*K[y][e], x in [g*16, g*16+16)
  {
    const int e = lane;
    float pr[16], pi[16];
#pragma unroll
    for (int i = 0; i < 16; ++i) { pr[i] = 0.f; pi[i] = 0.f; }
    for (int y = 0; y < 64; ++y) {
      const int ka = y * 64 + (e ^ (y & 31));
      const float kr = KP[0][ka], ki = KP[1][ka];
#pragma unroll
      for (int xi = 0; xi < 16; ++xi) {
        const int xx = g * 16 + xi;
        const int sa = xx * 64 + (y ^ (xx & 31));   // uniform -> broadcast
        const float srv = QS[0][sa], siv = QS[1][sa];
        pr[xi] = fmaf(srv, kr, fmaf(-siv, ki, pr[xi]));
        pi[xi] = fmaf(srv, ki, fmaf(siv, kr, pi[xi]));
      }
    }
    __syncthreads();
#pragma unroll
    for (int xi = 0; xi < 16; ++xi) {
      const int xx = g * 16 + xi;
      const int ad = xx * 64 + (e ^ (xx & 31));
      KP[0][ad] = pr[xi];
      KP[1][ad] = pi[xi];
    }
  }
  __syncthreads();

  // B3: thread (x=lane, g): O[o][x] = sum_e P[x][e]*w[e][o][x], o in [g*16, g*16+16)
  {
    const int xx = lane;
    float Or[16], Oi[16];
#pragma unroll
    for (int i = 0; i < 16; ++i) { Or[i] = 0.f; Oi[i] = 0.f; }
#pragma unroll 2
    for (int e = 0; e < 64; ++e) {
      const int pa = xx * 64 + (e ^ (xx & 31));
      const float ar = KP[0][pa], ai = KP[1][pa];
      const float* __restrict__ w1p = w1 + (size_t)((h * 64 + e) * 64 + g * 16) * 64 + xx;
      const float* __restrict__ w2p = w2 + (size_t)((h * 64 + e) * 64 + g * 16) * 64 + xx;
#pragma unroll
      for (int oi = 0; oi < 16; ++oi) {
        const float wr = w1p[oi * 64];   // lanes <-> x: coalesced
        const float wi = w2p[oi * 64];
        Or[oi] = fmaf(ar, wr, fmaf(-ai, wi, Or[oi]));
        Oi[oi] = fmaf(ar, wi, fmaf(ai, wr, Oi[oi]));
      }
    }
    const float gs = (xx == 0) ? 0x1p-30f : 0x1p-29f;   // 1/(512*512*4096), x2 for m>=1
#pragma unroll
    for (int oi = 0; oi < 16; ++oi) {
      const int o = g * 16 + oi;
      coefT[(size_t)(bh * 128 + 2 * xx) * 64 + o]     =  gs * Or[oi];
      coefT[(size_t)(bh * 128 + 2 * xx + 1) * 64 + o] = -gs * Oi[oi];
    }
  }
}

// Stage C: out[bh][o][t] = sum_j coefT[bh][j][o] * TW[j][t].
// grid 2048 = bh(64)|tc(16)|oh(2); block 256; thread<->t; 32 OUTPUT accumulators per thread
// (true accumulators -> cannot be rematerialized/spilled the way round-2's tw[128] was).
__global__ __launch_bounds__(256, 1) void idft_kernel(const float* __restrict__ coefT,
                                                      const float* __restrict__ twj,
                                                      float* __restrict__ out) {
  const int bh = blockIdx.x >> 5;
  const int tc = (blockIdx.x >> 1) & 15;
  const int oh = blockIdx.x & 1;
  const int t  = tc * 256 + threadIdx.x;

  float acc[32];
#pragma unroll
  for (int i = 0; i < 32; ++i) acc[i] = 0.f;

  const float* __restrict__ crow = coefT + (size_t)bh * 8192 + oh * 32;

#pragma unroll 2
  for (int j = 0; j < 128; ++j) {
    const float twv = twj[(size_t)j * 4096 + t];          // coalesced
    const float* __restrict__ cj = crow + (size_t)j * 64; // uniform -> broadcast
#pragma unroll
    for (int qd = 0; qd < 8; ++qd) {
      const float4 c4 = *(const float4*)(cj + qd * 4);
      acc[qd * 4 + 0] = fmaf(c4.x, twv, acc[qd * 4 + 0]);
      acc[qd * 4 + 1] = fmaf(c4.y, twv, acc[qd * 4 + 1]);
      acc[qd * 4 + 2] = fmaf(c4.z, twv, acc[qd * 4 + 2]);
      acc[qd * 4 + 3] = fmaf(c4.w, twv, acc[qd * 4 + 3]);
    }
  }

  float* __restrict__ orow = out + (size_t)bh * 262144 + (size_t)(oh * 32) * 4096 + t;
#pragma unroll
  for (int ol = 0; ol < 32; ++ol) {
    orow[(size_t)ol * 4096] = acc[ol];
  }
}

extern "C" void kernel_launch(void* const* d_in, const int* in_sizes, int n_in,
                              void* d_out, int out_size, void* d_ws, size_t ws_size,
                              hipStream_t stream) {
  (void)in_sizes; (void)n_in; (void)out_size; (void)ws_size;
  const float* q  = (const float*)d_in[0];
  const float* k  = (const float*)d_in[1];
  const float* w1 = (const float*)d_in[3];
  const float* w2 = (const float*)d_in[4];
  float* ws   = (float*)d_ws;
  float* outp = (float*)d_out;

  float* twa   = ws + TWA_OFF;
  float* twj   = ws + TWJ_OFF;
  float* qfp   = ws + QFP_OFF;
  float* coefT = ws + COEF_OFF;

  init_tw<<<256, 256, 0, stream>>>(twa);
  init_twj<<<2048, 256, 0, stream>>>(twj);
  dft_kernel<<<1024, 256, 0, stream>>>(q, k, twa, qfp);
  attn_kernel<<<64, 256, 0, stream>>>(qfp, w1, w2, coefT);
  idft_kernel<<<2048, 256, 0, stream>>>(coefT, twj, outp);
}